// Round 10
// baseline (183.280 us; speedup 1.0000x reference)
//
#include <hip/hip_runtime.h>
#include <hip/hip_bf16.h>
#include <cstdint>
#include <cmath>

typedef __bf16 bf16_t;
typedef __attribute__((ext_vector_type(8))) __bf16 bf16x8;
typedef __attribute__((ext_vector_type(4))) float f32x4;

#define LOG2E 1.4426950408889634f

constexpr int B_ = 2, T_ = 2048, C_ = 1024, H_ = 16, HD_ = 64, HD2_ = 32;
constexpr int M_ = B_ * T_;  // 4096

static __device__ __forceinline__ f32x4 mfma16(bf16x8 a, bf16x8 b, f32x4 c) {
    return __builtin_amdgcn_mfma_f32_16x16x32_bf16(a, b, c, 0, 0, 0);
}

// async global->LDS, 16B per lane; LDS dest = wave-uniform base + lane*16
#define GLL(gp, lp)                                                          \
    __builtin_amdgcn_global_load_lds(                                        \
        (const __attribute__((address_space(1))) void*)(gp),                 \
        (__attribute__((address_space(3))) void*)(lp), 16, 0, 0)

// explicit drain of this wave's outstanding GLL DMAs AND ds_reads before a staging
// barrier. R8 POST-MORTEM: relying on the compiler to emit waitcnts before
// s_barrier is NOT safe when the GLL issue is separated from the barrier by a
// compute phase (intermittent stale-LDS reads). vmcnt(0): this wave's GLL writes
// landed (RAW). lgkmcnt(0): this wave's ds_reads completed, so post-barrier GLLs
// from other waves cannot overwrite LDS under an in-flight read (WAR).
#define GLL_DRAIN() asm volatile("s_waitcnt vmcnt(0) lgkmcnt(0)" ::: "memory")

// ---------------- fused prep: cast x, transpose+cast both weights ----------------
// 2560 fat blocks (R7: dispatch-grain neutral; kept for simplicity).
__global__ __launch_bounds__(256) void prep(
    const float* __restrict__ x, bf16_t* __restrict__ xb,
    const float* __restrict__ Wqkv, bf16_t* __restrict__ wqkvT,
    const float* __restrict__ Wproj, bf16_t* __restrict__ wprojT) {
    __shared__ float tile[32][33];
    const int bid = blockIdx.x, tid = threadIdx.x;
    if (bid < 512) {  // cast x: 4M floats = 1M float4; 131072 threads x 8 iters
#pragma unroll
        for (int it = 0; it < 8; it++) {
            int i = it * 131072 + bid * 256 + tid;
            float4 v = ((const float4*)x)[i];
            bf16_t o[4] = {(bf16_t)v.x, (bf16_t)v.y, (bf16_t)v.z, (bf16_t)v.w};
            *(uint64_t*)(xb + (size_t)i * 4) = *(uint64_t*)o;
        }
        return;
    }
    const float* W;
    bf16_t* WT;
    int N, base;
    bool qkv = (bid < 512 + 1536);
    if (qkv) {
        W = Wqkv; WT = wqkvT; N = 3 * C_;
        base = (bid - 512) * 2;          // 3072 tiles, 2 per block
    } else {
        W = Wproj; WT = wprojT; N = C_;
        base = (bid - 2048) * 2;         // 1024 tiles, 2 per block
    }
    const int tx = tid & 31, ty = tid >> 5;
    for (int u = 0; u < 2; u++) {
        int tt = base + u;
        int nb, kb;
        if (qkv) { nb = (tt % 96) * 32; kb = (tt / 96) * 32; }
        else     { nb = (tt & 31) * 32; kb = (tt >> 5) * 32; }
        __syncthreads();  // tile reuse across u (no-op cost at u=0)
        for (int i = ty; i < 32; i += 8)
            tile[i][tx] = W[(size_t)(kb + i) * N + nb + tx];
        __syncthreads();
        for (int i = ty; i < 32; i += 8)
            WT[(size_t)(nb + i) * C_ + kb + tx] = (bf16_t)tile[tx][i];
    }
}

// ---------------- GEMM: C[m][n] = A[m][:] . BT[n][:] + bias ----------------
// R10 (= R9 + lgkmcnt in drain): dbuf K-loop, prefetch tile t+1 right after the
// barrier, compute tile t; each GLL_DRAIN covers loads issued one full compute
// phase earlier (~free). 1 barrier per K-tile. Correctness independent of the
// compiler's pre-barrier waitcnt policy (both RAW and WAR closed explicitly).
// MODE 0: 64 KB LDS, 2 blocks/CU; tile 128x128 (NT=4), 768 blocks; qkv epilogue
//         (Q bias+RoPE *log2e/8; K bias+RoPE swizzled; V -> VTb swizzled).
// MODE 1: 48 KB LDS, 3 blocks/CU; tile 128x64 (NT=2), 512 blocks; fp32 out + bias.
// LDS 16B-chunk XOR-(row&7) swizzle via pre-swizzled GLOBAL source (unchanged).
template <int MODE>
__global__ __launch_bounds__(256, (MODE == 1) ? 3 : 2) void gemm128(
    const bf16_t* __restrict__ A, const bf16_t* __restrict__ BT, const float* __restrict__ bias,
    int N, int K,
    bf16_t* __restrict__ Qb, bf16_t* __restrict__ Kb, bf16_t* __restrict__ VTb,
    const float* __restrict__ cosT, const float* __restrict__ sinT, float* __restrict__ out) {
    constexpr int NT = (MODE == 1) ? 2 : 4;          // 16-col frags per wave
    constexpr int BPARTS = (MODE == 1) ? 2 : 4;      // 32-row staging parts of B
    __shared__ alignas(16) bf16_t As[2][128 * 64];
    __shared__ alignas(16) bf16_t Bs[2][32 * BPARTS * 64];
    const int tid = threadIdx.x;
    const int w = tid >> 6, lane = tid & 63;
    const int quad = lane >> 4, r = lane & 15;
    const int wm = (w >> 1) * 64, wn = (w & 1) * (16 * NT);
    // XCD-partitioned decode: 8 XCDs as 4(m) x 2(n).
    const int bid = blockIdx.x;
    const int xcd = bid & 7, s = bid >> 3;
    int mb, nb;
    if (MODE == 0) {
        mb = (((xcd >> 1) << 3) + (s & 7)) << 7;         // 32 m-tiles of 128
        nb = (((xcd & 1) * 12 + (s >> 3))) << 7;         // 24 n-tiles of 128
    } else {
        mb = (((xcd >> 1) << 3) + (s & 7)) << 7;         // 32 m-tiles of 128
        nb = (((xcd & 1) << 3) + (s >> 3)) << 6;         // 16 n-tiles of 64
    }
    const int srow = tid >> 3, schunk = tid & 7;         // 32 rows x 8 chunks per part
    const int csw = (schunk ^ (srow & 7)) * 8;           // staged (swizzled) chunk
    const int koff0 = (quad ^ (r & 7)) * 8;              // frag de-swizzle, k-half 0
    const int koff1 = ((quad + 4) ^ (r & 7)) * 8;        // k-half 1

    f32x4 acc[4][NT] = {};

    const bf16_t* gA[4];
    const bf16_t* gB[BPARTS];
#pragma unroll
    for (int p = 0; p < 4; p++) gA[p] = A + (size_t)(mb + p * 32 + srow) * K + csw;
#pragma unroll
    for (int p = 0; p < BPARTS; p++) gB[p] = BT + (size_t)(nb + p * 32 + srow) * K + csw;

    // stage K-tile at offset k into buffer b
    auto stage = [&](int b, int k) {
#pragma unroll
        for (int p = 0; p < 4; p++) GLL(gA[p] + k, &As[b][0] + p * 2048 + tid * 8);
#pragma unroll
        for (int p = 0; p < BPARTS; p++) GLL(gB[p] + k, &Bs[b][0] + p * 2048 + tid * 8);
    };
    // compute one K-tile from buffer b
    auto compute = [&](int b) {
#pragma unroll
        for (int h = 0; h < 2; h++) {
            const int ko = h ? koff1 : koff0;
            bf16x8 af[4], bfr[NT];
#pragma unroll
            for (int i = 0; i < 4; i++)
                af[i] = *(const bf16x8*)(&As[b][0] + (wm + i * 16 + r) * 64 + ko);
#pragma unroll
            for (int j = 0; j < NT; j++)
                bfr[j] = *(const bf16x8*)(&Bs[b][0] + (wn + j * 16 + r) * 64 + ko);
#pragma unroll
            for (int i = 0; i < 4; i++)
#pragma unroll
                for (int j = 0; j < NT; j++) acc[i][j] = mfma16(af[i], bfr[j], acc[i][j]);
        }
    };

    stage(0, 0);  // prologue: tile 0 -> buf0
    for (int k0 = 0; k0 < K; k0 += 128) {
        GLL_DRAIN();      // buf0's GLLs landed; this wave's ds_reads done
        __syncthreads();  // + all waves at same point
        if (k0 + 64 < K) stage(1, k0 + 64);
        compute(0);
        GLL_DRAIN();      // buf1's GLLs landed; this wave's ds_reads done
        __syncthreads();
        if (k0 + 128 < K) stage(0, k0 + 128);
        compute(1);
    }

    if (MODE == 0) {
        const int col_base = nb + wn;          // multiple of 64 -> one head
        const int region = col_base >> 10;     // 0=q 1=k 2=v
        const int h = (col_base & 1023) >> 6;
        const float qscale = 0.125f * LOG2E;   // fold 1/sqrt(64) and log2(e) into q
        if (region < 2) {
#pragma unroll
            for (int i = 0; i < 4; i++) {
#pragma unroll
                for (int g = 0; g < 4; g++) {
                    int m = mb + wm + i * 16 + quad * 4 + g;
                    int b = m >> 11, t = m & (T_ - 1);
                    bf16_t* dst = (region == 0 ? Qb : Kb) + ((size_t)((b * H_ + h) * T_ + t)) * 64;
                    int tw = t & 7;
#pragma unroll
                    for (int j = 0; j < 2; j++) {
                        int d = j * 16 + r;
                        float u1 = acc[i][j][g] + bias[col_base + d];
                        float u2 = acc[i][j + 2][g] + bias[col_base + d + 32];
                        float c = cosT[t * HD2_ + d], s2 = sinT[t * HD2_ + d];
                        float o1 = u1 * c - u2 * s2;
                        float o2 = u1 * s2 + u2 * c;
                        if (region == 0) {
                            dst[d] = (bf16_t)(o1 * qscale);
                            dst[d + 32] = (bf16_t)(o2 * qscale);
                        } else {  // K: chunk-swizzled within row
                            dst[((((d >> 3) ^ tw)) << 3) | (d & 7)] = (bf16_t)o1;
                            dst[(((((d + 32) >> 3) ^ tw)) << 3) | (d & 7)] = (bf16_t)o2;
                        }
                    }
                }
            }
        } else {  // V -> VT, chunk-swizzled within each 64-col tile, 8B packed stores
#pragma unroll
            for (int i = 0; i < 4; i++) {
                int m0 = mb + wm + i * 16 + quad * 4;
                int b = m0 >> 11, t0 = m0 & (T_ - 1);
                bf16_t* base = VTb + (size_t)(b * H_ + h) * 64 * T_;
#pragma unroll
                for (int j = 0; j < 4; j++) {
                    int d = j * 16 + r;
                    float bb = bias[col_base + d];
                    bf16_t pk[4];
#pragma unroll
                    for (int g = 0; g < 4; g++) pk[g] = (bf16_t)(acc[i][j][g] + bb);
                    int c = (((t0 >> 3) & 7) ^ (d & 7));
                    int tsw = (t0 & ~63) | (c << 3) | (t0 & 7);
                    *(uint64_t*)(base + (size_t)d * T_ + tsw) = *(uint64_t*)pk;
                }
            }
        }
    } else {
#pragma unroll
        for (int i = 0; i < 4; i++)
#pragma unroll
            for (int g = 0; g < 4; g++) {
                int m = mb + wm + i * 16 + quad * 4 + g;
#pragma unroll
                for (int j = 0; j < NT; j++) {
                    int col = nb + wn + j * 16 + r;
                    out[(size_t)m * N + col] = acc[i][j][g] + bias[col];
                }
            }
    }
}

// ---------------- flash attention (causal), split-K, NO online max ----------------
// v3 (best measured): 4 waves/block (256 thr), q-tile = 64 rows, grp = w>>1 takes
// even/odd KV tiles, wq = w&1 owns 32 q-rows (2 B-frags). 80 KB LDS -> 2 blocks/CU.
// R5/R6 established: further DS-traffic cuts (v4: -33% DS/MFMA) are NEUTRAL -- attn
// is not DS-throughput-bound; keep this variant.
__global__ __launch_bounds__(256, 2) void attn64(
    const bf16_t* __restrict__ Qb, const bf16_t* __restrict__ Kb,
    const bf16_t* __restrict__ VTb, bf16_t* __restrict__ att) {
    __shared__ alignas(16) bf16_t Ks[2][2][4096];  // [buf][tile parity][64x64]
    __shared__ alignas(16) bf16_t Vs[2][2][4096];
    __shared__ alignas(16) bf16_t Ps[4][2048];     // per-wave P^T, 2 jq frames
    const int tid = threadIdx.x;
    const int w = tid >> 6, lane = tid & 63;
    const int grp = w >> 1, wq = w & 1;            // 2 tile-groups x 2 q-slices of 32
    const int quad = lane >> 4, r = lane & 15;
    const int id = blockIdx.x;
    const int t = 31 - (id >> 5);   // descending length
    const int bh = id & 31;
    const int ntiles = t + 1, nstages = (t + 2) >> 1;
    const size_t kbase = (size_t)bh * T_ * 64;
    const size_t vbase = (size_t)bh * 64 * T_;
    bf16_t* Pw = &Ps[w][0];
    const int srow = tid >> 3, schunk = tid & 7;  // staging: 32 rows x 8 chunks = 256 thr
    const int koff0 = ((quad ^ (r & 7)) * 8);
    const int koff1 = (((quad + 4) ^ (r & 7)) * 8);

    const int qbase = t * 64 + wq * 32;
    const int qrow0 = qbase + r, qrow1 = qbase + 16 + r;  // this wave's 2 q-frags
    bf16x8 qf00 = *(const bf16x8*)(Qb + kbase + (size_t)qrow0 * 64 + quad * 8);
    bf16x8 qf01 = *(const bf16x8*)(Qb + kbase + (size_t)qrow0 * 64 + 32 + quad * 8);
    bf16x8 qf10 = *(const bf16x8*)(Qb + kbase + (size_t)qrow1 * 64 + quad * 8);
    bf16x8 qf11 = *(const bf16x8*)(Qb + kbase + (size_t)qrow1 * 64 + 32 + quad * 8);

    f32x4 oacc[4][2] = {};
    float l0 = 0.f, l1 = 0.f;  // per-lane partial row-sums, one per q-frag

    // stage s=0 (tiles 0 and 1); 256 threads -> 2 sweeps of 32 rows per 64x64 tile
    {
        const bf16_t* kg = Kb + kbase + (size_t)srow * 64 + schunk * 8;
        const bf16_t* vg = VTb + vbase + (size_t)srow * T_ + schunk * 8;
        GLL(kg, &Ks[0][0][0] + tid * 8);
        GLL(kg + 2048, &Ks[0][0][0] + 2048 + tid * 8);
        GLL(vg, &Vs[0][0][0] + tid * 8);
        GLL(vg + 32 * T_, &Vs[0][0][0] + 2048 + tid * 8);
        if (1 < ntiles) {
            GLL(kg + 4096, &Ks[0][1][0] + tid * 8);
            GLL(kg + 4096 + 2048, &Ks[0][1][0] + 2048 + tid * 8);
            GLL(vg + 64, &Vs[0][1][0] + tid * 8);
            GLL(vg + 32 * T_ + 64, &Vs[0][1][0] + 2048 + tid * 8);
        }
    }
    for (int s = 0; s < nstages; s++) {
        const int cur = s & 1;
        GLL_DRAIN();      // buf[cur]'s GLLs landed + own ds_reads done (explicit)
        __syncthreads();  // + buf[cur^1] readers done
        if (s + 1 < nstages) {
            const int ja = 2 * (s + 1);
            const bf16_t* kg = Kb + kbase + (size_t)(ja * 64 + srow) * 64 + schunk * 8;
            const bf16_t* vg = VTb + vbase + (size_t)srow * T_ + ja * 64 + schunk * 8;
            GLL(kg, &Ks[cur ^ 1][0][0] + tid * 8);
            GLL(kg + 2048, &Ks[cur ^ 1][0][0] + 2048 + tid * 8);
            GLL(vg, &Vs[cur ^ 1][0][0] + tid * 8);
            GLL(vg + 32 * T_, &Vs[cur ^ 1][0][0] + 2048 + tid * 8);
            if (ja + 1 < ntiles) {
                GLL(kg + 4096, &Ks[cur ^ 1][1][0] + tid * 8);
                GLL(kg + 4096 + 2048, &Ks[cur ^ 1][1][0] + 2048 + tid * 8);
                GLL(vg + 64, &Vs[cur ^ 1][1][0] + tid * 8);
                GLL(vg + 32 * T_ + 64, &Vs[cur ^ 1][1][0] + 2048 + tid * 8);
            }
        }
        const int jt = 2 * s + grp;
        if (jt < ntiles) {
            const bf16_t* Kt = &Ks[cur][grp][0];
            const bf16_t* Vt = &Vs[cur][grp][0];
            // S^T = K Q^T : each K frag pair feeds BOTH q-frags
            f32x4 sc[4][2];
            __builtin_amdgcn_s_setprio(1);
#pragma unroll
            for (int m0 = 0; m0 < 4; m0++) {
                const bf16_t* kp = Kt + (m0 * 16 + r) * 64;
                bf16x8 kf0 = *(const bf16x8*)(kp + koff0);
                bf16x8 kf1 = *(const bf16x8*)(kp + koff1);
                f32x4 z0 = {0.f, 0.f, 0.f, 0.f};
                z0 = mfma16(kf0, qf00, z0);
                z0 = mfma16(kf1, qf01, z0);
                sc[m0][0] = z0;
                f32x4 z1 = {0.f, 0.f, 0.f, 0.f};
                z1 = mfma16(kf0, qf10, z1);
                z1 = mfma16(kf1, qf11, z1);
                sc[m0][1] = z1;
            }
            __builtin_amdgcn_s_setprio(0);
            if (jt == t) {  // causal mask on diagonal tile (exp2(-inf)=0)
                const int j0 = jt * 64;
#pragma unroll
                for (int m0 = 0; m0 < 4; m0++) {
                    int kvb = j0 + m0 * 16 + quad * 4;
#pragma unroll
                    for (int g = 0; g < 4; g++) {
                        if (kvb + g > qrow0) sc[m0][0][g] = -INFINITY;
                        if (kvb + g > qrow1) sc[m0][1][g] = -INFINITY;
                    }
                }
            }
            // stateless softmax: p = exp2(s), partial l per q-frag
            float rs0 = 0.f, rs1 = 0.f;
#pragma unroll
            for (int m0 = 0; m0 < 4; m0++)
#pragma unroll
                for (int g = 0; g < 4; g++) {
                    float p0 = __builtin_amdgcn_exp2f(sc[m0][0][g]);
                    float p1 = __builtin_amdgcn_exp2f(sc[m0][1][g]);
                    sc[m0][0][g] = p0;
                    sc[m0][1][g] = p1;
                    rs0 += p0;
                    rs1 += p1;
                }
            l0 += rs0;
            l1 += rs1;
            // P^T -> per-wave LDS (packed b64), read back as B-frags (2 jq frames)
#pragma unroll
            for (int jq = 0; jq < 2; jq++)
#pragma unroll
                for (int m0 = 0; m0 < 4; m0++) {
                    bf16_t hq[4];
#pragma unroll
                    for (int g = 0; g < 4; g++) hq[g] = (bf16_t)sc[m0][jq][g];
                    int elem = jq * 1024 + (m0 >> 1) * 512 +
                               (((m0 & 1) * 2 + (quad >> 1)) * 16 + r) * 8 + (quad & 1) * 4;
                    *(uint64_t*)(Pw + elem) = *(uint64_t*)hq;
                }
            __builtin_amdgcn_wave_barrier();  // Pw writes -> reads (same wave, DS in-order)
            bf16x8 pf00 = *(const bf16x8*)(Pw + lane * 8);
            bf16x8 pf01 = *(const bf16x8*)(Pw + 512 + lane * 8);
            bf16x8 pf10 = *(const bf16x8*)(Pw + 1024 + lane * 8);
            bf16x8 pf11 = *(const bf16x8*)(Pw + 1536 + lane * 8);
            __builtin_amdgcn_s_setprio(1);
#pragma unroll
            for (int d0 = 0; d0 < 4; d0++) {
                const bf16_t* vp = Vt + (d0 * 16 + r) * 64;
                bf16x8 vf0 = *(const bf16x8*)(vp + koff0);
                bf16x8 vf1 = *(const bf16x8*)(vp + koff1);
                oacc[d0][0] = mfma16(vf0, pf00, oacc[d0][0]);
                oacc[d0][0] = mfma16(vf1, pf01, oacc[d0][0]);
                oacc[d0][1] = mfma16(vf0, pf10, oacc[d0][1]);
                oacc[d0][1] = mfma16(vf1, pf11, oacc[d0][1]);
            }
            __builtin_amdgcn_s_setprio(0);
            // no trailing wave_barrier: next stage's Pw writes are same-wave DS ops,
            // issued after these reads -> DS pipe order guarantees WAR safety.
        }
    }
    // full row-sums: reduce l across the 4 quads (deferred from the loop)
    l0 += __shfl_xor(l0, 16);
    l0 += __shfl_xor(l0, 32);
    l1 += __shfl_xor(l1, 16);
    l1 += __shfl_xor(l1, 32);
    // ---- combine group partials (split-K merge) ----
    GLL_DRAIN();      // any tail prefetch landed before LDS reuse
    __syncthreads();  // all staging/P traffic done; LDS reusable
    float* Co = (float*)&Ks[0][0][0];  // O1: [2wq][2jq][16q][64d] fp32 = 16 KB
    float* Cl = (float*)&Vs[0][0][0];  // l1[64]
    if (grp == 1) {
#pragma unroll
        for (int jq = 0; jq < 2; jq++)
#pragma unroll
            for (int d0 = 0; d0 < 4; d0++)
                *(f32x4*)(Co + ((wq * 2 + jq) * 16 + r) * 64 + d0 * 16 + quad * 4) =
                    oacc[d0][jq];
        if (quad == 0) {
            Cl[(wq * 2) * 16 + r] = l0;
            Cl[(wq * 2 + 1) * 16 + r] = l1;
        }
    }
    __syncthreads();
    if (grp == 0) {
        const int b = bh >> 4, h = bh & 15;
#pragma unroll
        for (int jq = 0; jq < 2; jq++) {
            float lsum = (jq ? l1 : l0) + Cl[(wq * 2 + jq) * 16 + r];
            float inv = 1.f / lsum;
            const int qrow = qbase + jq * 16 + r;
            bf16_t* dst = att + ((size_t)(b * T_ + qrow)) * 1024 + h * 64;
#pragma unroll
            for (int d0 = 0; d0 < 4; d0++) {
                f32x4 o1 =
                    *(const f32x4*)(Co + ((wq * 2 + jq) * 16 + r) * 64 + d0 * 16 + quad * 4);
                bf16_t hh[4];
#pragma unroll
                for (int g = 0; g < 4; g++)
                    hh[g] = (bf16_t)((oacc[d0][jq][g] + o1[g]) * inv);
                *(uint64_t*)(dst + d0 * 16 + quad * 4) = *(uint64_t*)hh;
            }
        }
    }
}

// ---------------- launch ----------------
extern "C" void kernel_launch(void* const* d_in, const int* in_sizes, int n_in,
                              void* d_out, int out_size, void* d_ws, size_t ws_size,
                              hipStream_t stream) {
    const float* x = (const float*)d_in[0];
    const float* fcos = (const float*)d_in[1];
    const float* fsin = (const float*)d_in[2];
    const float* Wqkv = (const float*)d_in[3];
    const float* bqkv = (const float*)d_in[4];
    const float* Wproj = (const float*)d_in[5];
    const float* bproj = (const float*)d_in[6];
    float* out = (float*)d_out;

    uint8_t* p = (uint8_t*)d_ws;
    size_t need = 0;
    auto take = [&](size_t bytes) {
        void* q = p;
        size_t pad = (bytes + 255) & ~(size_t)255;
        p += pad;
        need += pad;
        return q;
    };
    bf16_t* xb = (bf16_t*)take((size_t)M_ * C_ * 2);         // 8 MB
    bf16_t* wqkvT = (bf16_t*)take((size_t)3 * C_ * C_ * 2);  // 6 MB
    bf16_t* wprojT = (bf16_t*)take((size_t)C_ * C_ * 2);     // 2 MB
    bf16_t* Qb = (bf16_t*)take((size_t)B_ * H_ * T_ * 64 * 2);
    bf16_t* Kb = (bf16_t*)take((size_t)B_ * H_ * T_ * 64 * 2);
    bf16_t* VTb = (bf16_t*)take((size_t)B_ * H_ * 64 * T_ * 2);
    bf16_t* attb = (bf16_t*)take((size_t)M_ * C_ * 2);
    if (ws_size < need) return;  // fail loudly (zeros) rather than corrupt

    // fused prep: cast x (512 blocks, grid-strided) + transpose Wqkv (1536) +
    // transpose Wproj (512) -- 2560 fat blocks total
    prep<<<2560, 256, 0, stream>>>(x, xb, Wqkv, wqkvT, Wproj, wprojT);

    // QKV GEMM + bias + RoPE + swizzled scatter (768 blocks, dbuf K-loop w/
    // explicit two-counter drains, 2/CU)
    gemm128<0><<<dim3(768), 256, 0, stream>>>(
        xb, wqkvT, bqkv, 3 * C_, C_, Qb, Kb, VTb, fcos, fsin, nullptr);

    // flash attention: 4 waves/block, 32 q-rows/wave, split-K pairs of KV tiles,
    // descending-t LPT dispatch (1024 blocks, 2 blocks/CU, 80 KB LDS)
    attn64<<<dim3(1024), 256, 0, stream>>>(Qb, Kb, VTb, attb);

    // output projection (512 blocks of 128x64, dbuf K-loop w/ explicit drains, 3/CU)
    gemm128<1><<<dim3(512), 256, 0, stream>>>(
        attb, wprojT, bproj, C_, C_, nullptr, nullptr, nullptr, nullptr, nullptr, out);
}

// Round 11
// 169.869 us; speedup vs baseline: 1.0790x; 1.0790x over previous
//
#include <hip/hip_runtime.h>
#include <hip/hip_bf16.h>
#include <cstdint>
#include <cmath>

typedef __bf16 bf16_t;
typedef __attribute__((ext_vector_type(8))) __bf16 bf16x8;
typedef __attribute__((ext_vector_type(4))) float f32x4;

#define LOG2E 1.4426950408889634f

constexpr int B_ = 2, T_ = 2048, C_ = 1024, H_ = 16, HD_ = 64, HD2_ = 32;
constexpr int M_ = B_ * T_;  // 4096

static __device__ __forceinline__ f32x4 mfma16(bf16x8 a, bf16x8 b, f32x4 c) {
    return __builtin_amdgcn_mfma_f32_16x16x32_bf16(a, b, c, 0, 0, 0);
}

// async global->LDS, 16B per lane; LDS dest = wave-uniform base + lane*16
#define GLL(gp, lp)                                                          \
    __builtin_amdgcn_global_load_lds(                                        \
        (const __attribute__((address_space(1))) void*)(gp),                 \
        (__attribute__((address_space(3))) void*)(lp), 16, 0, 0)

// ---------------- fused prep: cast x, transpose+cast both weights ----------------
// 2560 fat blocks (R7: dispatch-grain neutral; kept).
__global__ __launch_bounds__(256) void prep(
    const float* __restrict__ x, bf16_t* __restrict__ xb,
    const float* __restrict__ Wqkv, bf16_t* __restrict__ wqkvT,
    const float* __restrict__ Wproj, bf16_t* __restrict__ wprojT) {
    __shared__ float tile[32][33];
    const int bid = blockIdx.x, tid = threadIdx.x;
    if (bid < 512) {  // cast x: 4M floats = 1M float4; 131072 threads x 8 iters
#pragma unroll
        for (int it = 0; it < 8; it++) {
            int i = it * 131072 + bid * 256 + tid;
            float4 v = ((const float4*)x)[i];
            bf16_t o[4] = {(bf16_t)v.x, (bf16_t)v.y, (bf16_t)v.z, (bf16_t)v.w};
            *(uint64_t*)(xb + (size_t)i * 4) = *(uint64_t*)o;
        }
        return;
    }
    const float* W;
    bf16_t* WT;
    int N, base;
    bool qkv = (bid < 512 + 1536);
    if (qkv) {
        W = Wqkv; WT = wqkvT; N = 3 * C_;
        base = (bid - 512) * 2;          // 3072 tiles, 2 per block
    } else {
        W = Wproj; WT = wprojT; N = C_;
        base = (bid - 2048) * 2;         // 1024 tiles, 2 per block
    }
    const int tx = tid & 31, ty = tid >> 5;
    for (int u = 0; u < 2; u++) {
        int tt = base + u;
        int nb, kb;
        if (qkv) { nb = (tt % 96) * 32; kb = (tt / 96) * 32; }
        else     { nb = (tt & 31) * 32; kb = (tt >> 5) * 32; }
        __syncthreads();  // tile reuse across u (no-op cost at u=0)
        for (int i = ty; i < 32; i += 8)
            tile[i][tx] = W[(size_t)(kb + i) * N + nb + tx];
        __syncthreads();
        for (int i = ty; i < 32; i += 8)
            WT[(size_t)(nb + i) * C_ + kb + tx] = (bf16_t)tile[tx][i];
    }
}

// ---------------- GEMM: C[m][n] = A[m][:] . BT[n][:] + bias ----------------
// FINAL (R10 post-mortem): single-buffer K-loop, 2 barriers/K-step, 32 KB LDS,
// 3 blocks/CU. This is the best-measured structure (46 us MODE-0, MfmaUtil 21%).
// Both pipelining alternatives were measured WORSE on this toolchain:
//  - 8-phase 256^2 counted-vmcnt (R4): 67 us, MfmaUtil 14% (lockstep serialization,
//    1 block/CU, shallow prefetch).
//  - dbuf + explicit vmcnt/lgkmcnt drains (R10): 67 us, MfmaUtil 14% (64 KB LDS
//    drops to 2 blocks/CU; 1-phase prefetch depth < L2/HBM latency; asm drains pin
//    the schedule). The implicit 3-blocks/CU wave overlap (m114) is worth more.
//  - dbuf WITHOUT explicit drains (R8): RACE -- compiler does not reliably emit
//    vmcnt(0) before s_barrier when GLL issue is separated from the barrier.
// LDS 16B-chunk XOR-(row&7) swizzle applied on the GLOBAL source address so the
// GLL-staged image gives 2-way (free) bank spread on strided frag reads.
// MODE 0: tile 128x128 (NT=4), 768 blocks XCD-partitioned; qkv epilogue
//         (Q bias+RoPE *log2e/8; K bias+RoPE swizzled; V -> VTb swizzled).
// MODE 1: tile 128x64 (NT=2), 512 blocks XCD-partitioned; fp32 out + bias.
template <int MODE>
__global__ __launch_bounds__(256, 3) void gemm128(
    const bf16_t* __restrict__ A, const bf16_t* __restrict__ BT, const float* __restrict__ bias,
    int N, int K,
    bf16_t* __restrict__ Qb, bf16_t* __restrict__ Kb, bf16_t* __restrict__ VTb,
    const float* __restrict__ cosT, const float* __restrict__ sinT, float* __restrict__ out) {
    constexpr int NT = (MODE == 1) ? 2 : 4;          // 16-col frags per wave
    constexpr int BPARTS = (MODE == 1) ? 2 : 4;      // 32-row staging parts of B
    __shared__ alignas(16) bf16_t As[128 * 64];
    __shared__ alignas(16) bf16_t Bs[32 * BPARTS * 64];
    const int tid = threadIdx.x;
    const int w = tid >> 6, lane = tid & 63;
    const int quad = lane >> 4, r = lane & 15;
    const int wm = (w >> 1) * 64, wn = (w & 1) * (16 * NT);
    // XCD-partitioned decode: 8 XCDs as 4(m) x 2(n).
    const int bid = blockIdx.x;
    const int xcd = bid & 7, s = bid >> 3;
    int mb, nb;
    if (MODE == 0) {
        mb = (((xcd >> 1) << 3) + (s & 7)) << 7;         // 32 m-tiles of 128
        nb = (((xcd & 1) * 12 + (s >> 3))) << 7;         // 24 n-tiles of 128
    } else {
        mb = (((xcd >> 1) << 3) + (s & 7)) << 7;         // 32 m-tiles of 128
        nb = (((xcd & 1) << 3) + (s >> 3)) << 6;         // 16 n-tiles of 64
    }
    const int srow = tid >> 3, schunk = tid & 7;         // 32 rows x 8 chunks per part
    const int csw = (schunk ^ (srow & 7)) * 8;           // staged (swizzled) chunk
    const int koff0 = (quad ^ (r & 7)) * 8;              // frag de-swizzle, k-half 0
    const int koff1 = ((quad + 4) ^ (r & 7)) * 8;        // k-half 1

    f32x4 acc[4][NT] = {};

    const bf16_t* gA[4];
    const bf16_t* gB[BPARTS];
#pragma unroll
    for (int p = 0; p < 4; p++) gA[p] = A + (size_t)(mb + p * 32 + srow) * K + csw;
#pragma unroll
    for (int p = 0; p < BPARTS; p++) gB[p] = BT + (size_t)(nb + p * 32 + srow) * K + csw;

    for (int k0 = 0; k0 < K; k0 += 64) {
        __syncthreads();  // previous iter's LDS reads done
#pragma unroll
        for (int p = 0; p < 4; p++) GLL(gA[p] + k0, As + p * 2048 + tid * 8);
#pragma unroll
        for (int p = 0; p < BPARTS; p++) GLL(gB[p] + k0, Bs + p * 2048 + tid * 8);
        __syncthreads();  // drains vmcnt -> LDS populated (compiler emits the wait here)
#pragma unroll
        for (int h = 0; h < 2; h++) {
            const int ko = h ? koff1 : koff0;
            bf16x8 af[4], bfr[NT];
#pragma unroll
            for (int i = 0; i < 4; i++) af[i] = *(const bf16x8*)(As + (wm + i * 16 + r) * 64 + ko);
#pragma unroll
            for (int j = 0; j < NT; j++) bfr[j] = *(const bf16x8*)(Bs + (wn + j * 16 + r) * 64 + ko);
#pragma unroll
            for (int i = 0; i < 4; i++)
#pragma unroll
                for (int j = 0; j < NT; j++) acc[i][j] = mfma16(af[i], bfr[j], acc[i][j]);
        }
    }

    if (MODE == 0) {
        const int col_base = nb + wn;          // multiple of 64 -> one head
        const int region = col_base >> 10;     // 0=q 1=k 2=v
        const int h = (col_base & 1023) >> 6;
        const float qscale = 0.125f * LOG2E;   // fold 1/sqrt(64) and log2(e) into q
        if (region < 2) {
#pragma unroll
            for (int i = 0; i < 4; i++) {
#pragma unroll
                for (int g = 0; g < 4; g++) {
                    int m = mb + wm + i * 16 + quad * 4 + g;
                    int b = m >> 11, t = m & (T_ - 1);
                    bf16_t* dst = (region == 0 ? Qb : Kb) + ((size_t)((b * H_ + h) * T_ + t)) * 64;
                    int tw = t & 7;
#pragma unroll
                    for (int j = 0; j < 2; j++) {
                        int d = j * 16 + r;
                        float u1 = acc[i][j][g] + bias[col_base + d];
                        float u2 = acc[i][j + 2][g] + bias[col_base + d + 32];
                        float c = cosT[t * HD2_ + d], s2 = sinT[t * HD2_ + d];
                        float o1 = u1 * c - u2 * s2;
                        float o2 = u1 * s2 + u2 * c;
                        if (region == 0) {
                            dst[d] = (bf16_t)(o1 * qscale);
                            dst[d + 32] = (bf16_t)(o2 * qscale);
                        } else {  // K: chunk-swizzled within row
                            dst[((((d >> 3) ^ tw)) << 3) | (d & 7)] = (bf16_t)o1;
                            dst[(((((d + 32) >> 3) ^ tw)) << 3) | (d & 7)] = (bf16_t)o2;
                        }
                    }
                }
            }
        } else {  // V -> VT, chunk-swizzled within each 64-col tile, 8B packed stores
#pragma unroll
            for (int i = 0; i < 4; i++) {
                int m0 = mb + wm + i * 16 + quad * 4;
                int b = m0 >> 11, t0 = m0 & (T_ - 1);
                bf16_t* base = VTb + (size_t)(b * H_ + h) * 64 * T_;
#pragma unroll
                for (int j = 0; j < 4; j++) {
                    int d = j * 16 + r;
                    float bb = bias[col_base + d];
                    bf16_t pk[4];
#pragma unroll
                    for (int g = 0; g < 4; g++) pk[g] = (bf16_t)(acc[i][j][g] + bb);
                    int c = (((t0 >> 3) & 7) ^ (d & 7));
                    int tsw = (t0 & ~63) | (c << 3) | (t0 & 7);
                    *(uint64_t*)(base + (size_t)d * T_ + tsw) = *(uint64_t*)pk;
                }
            }
        }
    } else {
#pragma unroll
        for (int i = 0; i < 4; i++)
#pragma unroll
            for (int g = 0; g < 4; g++) {
                int m = mb + wm + i * 16 + quad * 4 + g;
#pragma unroll
                for (int j = 0; j < NT; j++) {
                    int col = nb + wn + j * 16 + r;
                    out[(size_t)m * N + col] = acc[i][j][g] + bias[col];
                }
            }
    }
}

// ---------------- flash attention (causal), split-K, NO online max ----------------
// v3 (best measured): 4 waves/block (256 thr), q-tile = 64 rows, grp = w>>1 takes
// even/odd KV tiles, wq = w&1 owns 32 q-rows (2 B-frags). 80 KB LDS -> 2 blocks/CU.
// R5/R6: further DS-traffic cuts (v4: -33% DS/MFMA) measured NEUTRAL -- attn is
// not DS-throughput-bound; keep this variant.
__global__ __launch_bounds__(256, 2) void attn64(
    const bf16_t* __restrict__ Qb, const bf16_t* __restrict__ Kb,
    const bf16_t* __restrict__ VTb, bf16_t* __restrict__ att) {
    __shared__ alignas(16) bf16_t Ks[2][2][4096];  // [buf][tile parity][64x64]
    __shared__ alignas(16) bf16_t Vs[2][2][4096];
    __shared__ alignas(16) bf16_t Ps[4][2048];     // per-wave P^T, 2 jq frames
    const int tid = threadIdx.x;
    const int w = tid >> 6, lane = tid & 63;
    const int grp = w >> 1, wq = w & 1;            // 2 tile-groups x 2 q-slices of 32
    const int quad = lane >> 4, r = lane & 15;
    const int id = blockIdx.x;
    const int t = 31 - (id >> 5);   // descending length
    const int bh = id & 31;
    const int ntiles = t + 1, nstages = (t + 2) >> 1;
    const size_t kbase = (size_t)bh * T_ * 64;
    const size_t vbase = (size_t)bh * 64 * T_;
    bf16_t* Pw = &Ps[w][0];
    const int srow = tid >> 3, schunk = tid & 7;  // staging: 32 rows x 8 chunks = 256 thr
    const int koff0 = ((quad ^ (r & 7)) * 8);
    const int koff1 = (((quad + 4) ^ (r & 7)) * 8);

    const int qbase = t * 64 + wq * 32;
    const int qrow0 = qbase + r, qrow1 = qbase + 16 + r;  // this wave's 2 q-frags
    bf16x8 qf00 = *(const bf16x8*)(Qb + kbase + (size_t)qrow0 * 64 + quad * 8);
    bf16x8 qf01 = *(const bf16x8*)(Qb + kbase + (size_t)qrow0 * 64 + 32 + quad * 8);
    bf16x8 qf10 = *(const bf16x8*)(Qb + kbase + (size_t)qrow1 * 64 + quad * 8);
    bf16x8 qf11 = *(const bf16x8*)(Qb + kbase + (size_t)qrow1 * 64 + 32 + quad * 8);

    f32x4 oacc[4][2] = {};
    float l0 = 0.f, l1 = 0.f;  // per-lane partial row-sums, one per q-frag

    // stage s=0 (tiles 0 and 1); 256 threads -> 2 sweeps of 32 rows per 64x64 tile
    {
        const bf16_t* kg = Kb + kbase + (size_t)srow * 64 + schunk * 8;
        const bf16_t* vg = VTb + vbase + (size_t)srow * T_ + schunk * 8;
        GLL(kg, &Ks[0][0][0] + tid * 8);
        GLL(kg + 2048, &Ks[0][0][0] + 2048 + tid * 8);
        GLL(vg, &Vs[0][0][0] + tid * 8);
        GLL(vg + 32 * T_, &Vs[0][0][0] + 2048 + tid * 8);
        if (1 < ntiles) {
            GLL(kg + 4096, &Ks[0][1][0] + tid * 8);
            GLL(kg + 4096 + 2048, &Ks[0][1][0] + 2048 + tid * 8);
            GLL(vg + 64, &Vs[0][1][0] + tid * 8);
            GLL(vg + 32 * T_ + 64, &Vs[0][1][0] + 2048 + tid * 8);
        }
    }
    for (int s = 0; s < nstages; s++) {
        const int cur = s & 1;
        __syncthreads();  // buf[cur] staged; buf[cur^1] readers done
        if (s + 1 < nstages) {
            const int ja = 2 * (s + 1);
            const bf16_t* kg = Kb + kbase + (size_t)(ja * 64 + srow) * 64 + schunk * 8;
            const bf16_t* vg = VTb + vbase + (size_t)srow * T_ + ja * 64 + schunk * 8;
            GLL(kg, &Ks[cur ^ 1][0][0] + tid * 8);
            GLL(kg + 2048, &Ks[cur ^ 1][0][0] + 2048 + tid * 8);
            GLL(vg, &Vs[cur ^ 1][0][0] + tid * 8);
            GLL(vg + 32 * T_, &Vs[cur ^ 1][0][0] + 2048 + tid * 8);
            if (ja + 1 < ntiles) {
                GLL(kg + 4096, &Ks[cur ^ 1][1][0] + tid * 8);
                GLL(kg + 4096 + 2048, &Ks[cur ^ 1][1][0] + 2048 + tid * 8);
                GLL(vg + 64, &Vs[cur ^ 1][1][0] + tid * 8);
                GLL(vg + 32 * T_ + 64, &Vs[cur ^ 1][1][0] + 2048 + tid * 8);
            }
        }
        const int jt = 2 * s + grp;
        if (jt < ntiles) {
            const bf16_t* Kt = &Ks[cur][grp][0];
            const bf16_t* Vt = &Vs[cur][grp][0];
            // S^T = K Q^T : each K frag pair feeds BOTH q-frags
            f32x4 sc[4][2];
            __builtin_amdgcn_s_setprio(1);
#pragma unroll
            for (int m0 = 0; m0 < 4; m0++) {
                const bf16_t* kp = Kt + (m0 * 16 + r) * 64;
                bf16x8 kf0 = *(const bf16x8*)(kp + koff0);
                bf16x8 kf1 = *(const bf16x8*)(kp + koff1);
                f32x4 z0 = {0.f, 0.f, 0.f, 0.f};
                z0 = mfma16(kf0, qf00, z0);
                z0 = mfma16(kf1, qf01, z0);
                sc[m0][0] = z0;
                f32x4 z1 = {0.f, 0.f, 0.f, 0.f};
                z1 = mfma16(kf0, qf10, z1);
                z1 = mfma16(kf1, qf11, z1);
                sc[m0][1] = z1;
            }
            __builtin_amdgcn_s_setprio(0);
            if (jt == t) {  // causal mask on diagonal tile (exp2(-inf)=0)
                const int j0 = jt * 64;
#pragma unroll
                for (int m0 = 0; m0 < 4; m0++) {
                    int kvb = j0 + m0 * 16 + quad * 4;
#pragma unroll
                    for (int g = 0; g < 4; g++) {
                        if (kvb + g > qrow0) sc[m0][0][g] = -INFINITY;
                        if (kvb + g > qrow1) sc[m0][1][g] = -INFINITY;
                    }
                }
            }
            // stateless softmax: p = exp2(s), partial l per q-frag
            float rs0 = 0.f, rs1 = 0.f;
#pragma unroll
            for (int m0 = 0; m0 < 4; m0++)
#pragma unroll
                for (int g = 0; g < 4; g++) {
                    float p0 = __builtin_amdgcn_exp2f(sc[m0][0][g]);
                    float p1 = __builtin_amdgcn_exp2f(sc[m0][1][g]);
                    sc[m0][0][g] = p0;
                    sc[m0][1][g] = p1;
                    rs0 += p0;
                    rs1 += p1;
                }
            l0 += rs0;
            l1 += rs1;
            // P^T -> per-wave LDS (packed b64), read back as B-frags (2 jq frames)
#pragma unroll
            for (int jq = 0; jq < 2; jq++)
#pragma unroll
                for (int m0 = 0; m0 < 4; m0++) {
                    bf16_t hq[4];
#pragma unroll
                    for (int g = 0; g < 4; g++) hq[g] = (bf16_t)sc[m0][jq][g];
                    int elem = jq * 1024 + (m0 >> 1) * 512 +
                               (((m0 & 1) * 2 + (quad >> 1)) * 16 + r) * 8 + (quad & 1) * 4;
                    *(uint64_t*)(Pw + elem) = *(uint64_t*)hq;
                }
            __builtin_amdgcn_wave_barrier();  // Pw writes -> reads (same wave, DS in-order)
            bf16x8 pf00 = *(const bf16x8*)(Pw + lane * 8);
            bf16x8 pf01 = *(const bf16x8*)(Pw + 512 + lane * 8);
            bf16x8 pf10 = *(const bf16x8*)(Pw + 1024 + lane * 8);
            bf16x8 pf11 = *(const bf16x8*)(Pw + 1536 + lane * 8);
            __builtin_amdgcn_s_setprio(1);
#pragma unroll
            for (int d0 = 0; d0 < 4; d0++) {
                const bf16_t* vp = Vt + (d0 * 16 + r) * 64;
                bf16x8 vf0 = *(const bf16x8*)(vp + koff0);
                bf16x8 vf1 = *(const bf16x8*)(vp + koff1);
                oacc[d0][0] = mfma16(vf0, pf00, oacc[d0][0]);
                oacc[d0][0] = mfma16(vf1, pf01, oacc[d0][0]);
                oacc[d0][1] = mfma16(vf0, pf10, oacc[d0][1]);
                oacc[d0][1] = mfma16(vf1, pf11, oacc[d0][1]);
            }
            __builtin_amdgcn_s_setprio(0);
            // no trailing wave_barrier: next stage's Pw writes are same-wave DS ops,
            // issued after these reads -> DS pipe order guarantees WAR safety.
        }
    }
    // full row-sums: reduce l across the 4 quads (deferred from the loop)
    l0 += __shfl_xor(l0, 16);
    l0 += __shfl_xor(l0, 32);
    l1 += __shfl_xor(l1, 16);
    l1 += __shfl_xor(l1, 32);
    // ---- combine group partials (split-K merge) ----
    __syncthreads();  // all staging/P traffic done; LDS reusable
    float* Co = (float*)&Ks[0][0][0];  // O1: [2wq][2jq][16q][64d] fp32 = 16 KB
    float* Cl = (float*)&Vs[0][0][0];  // l1[64]
    if (grp == 1) {
#pragma unroll
        for (int jq = 0; jq < 2; jq++)
#pragma unroll
            for (int d0 = 0; d0 < 4; d0++)
                *(f32x4*)(Co + ((wq * 2 + jq) * 16 + r) * 64 + d0 * 16 + quad * 4) =
                    oacc[d0][jq];
        if (quad == 0) {
            Cl[(wq * 2) * 16 + r] = l0;
            Cl[(wq * 2 + 1) * 16 + r] = l1;
        }
    }
    __syncthreads();
    if (grp == 0) {
        const int b = bh >> 4, h = bh & 15;
#pragma unroll
        for (int jq = 0; jq < 2; jq++) {
            float lsum = (jq ? l1 : l0) + Cl[(wq * 2 + jq) * 16 + r];
            float inv = 1.f / lsum;
            const int qrow = qbase + jq * 16 + r;
            bf16_t* dst = att + ((size_t)(b * T_ + qrow)) * 1024 + h * 64;
#pragma unroll
            for (int d0 = 0; d0 < 4; d0++) {
                f32x4 o1 =
                    *(const f32x4*)(Co + ((wq * 2 + jq) * 16 + r) * 64 + d0 * 16 + quad * 4);
                bf16_t hh[4];
#pragma unroll
                for (int g = 0; g < 4; g++)
                    hh[g] = (bf16_t)((oacc[d0][jq][g] + o1[g]) * inv);
                *(uint64_t*)(dst + d0 * 16 + quad * 4) = *(uint64_t*)hh;
            }
        }
    }
}

// ---------------- launch ----------------
extern "C" void kernel_launch(void* const* d_in, const int* in_sizes, int n_in,
                              void* d_out, int out_size, void* d_ws, size_t ws_size,
                              hipStream_t stream) {
    const float* x = (const float*)d_in[0];
    const float* fcos = (const float*)d_in[1];
    const float* fsin = (const float*)d_in[2];
    const float* Wqkv = (const float*)d_in[3];
    const float* bqkv = (const float*)d_in[4];
    const float* Wproj = (const float*)d_in[5];
    const float* bproj = (const float*)d_in[6];
    float* out = (float*)d_out;

    uint8_t* p = (uint8_t*)d_ws;
    size_t need = 0;
    auto take = [&](size_t bytes) {
        void* q = p;
        size_t pad = (bytes + 255) & ~(size_t)255;
        p += pad;
        need += pad;
        return q;
    };
    bf16_t* xb = (bf16_t*)take((size_t)M_ * C_ * 2);         // 8 MB
    bf16_t* wqkvT = (bf16_t*)take((size_t)3 * C_ * C_ * 2);  // 6 MB
    bf16_t* wprojT = (bf16_t*)take((size_t)C_ * C_ * 2);     // 2 MB
    bf16_t* Qb = (bf16_t*)take((size_t)B_ * H_ * T_ * 64 * 2);
    bf16_t* Kb = (bf16_t*)take((size_t)B_ * H_ * T_ * 64 * 2);
    bf16_t* VTb = (bf16_t*)take((size_t)B_ * H_ * 64 * T_ * 2);
    bf16_t* attb = (bf16_t*)take((size_t)M_ * C_ * 2);
    if (ws_size < need) return;  // fail loudly (zeros) rather than corrupt

    // fused prep: cast x (512 blocks, grid-strided) + transpose Wqkv (1536) +
    // transpose Wproj (512) -- 2560 fat blocks total
    prep<<<2560, 256, 0, stream>>>(x, xb, Wqkv, wqkvT, Wproj, wprojT);

    // QKV GEMM + bias + RoPE + swizzled scatter (768 blocks, XCD-partitioned, 3/CU)
    gemm128<0><<<dim3(768), 256, 0, stream>>>(
        xb, wqkvT, bqkv, 3 * C_, C_, Qb, Kb, VTb, fcos, fsin, nullptr);

    // flash attention: 4 waves/block, 32 q-rows/wave, split-K pairs of KV tiles,
    // descending-t LPT dispatch (1024 blocks, 2 blocks/CU, 80 KB LDS)
    attn64<<<dim3(1024), 256, 0, stream>>>(Qb, Kb, VTb, attb);

    // output projection (512 blocks of 128x64, XCD-partitioned, 3/CU)
    gemm128<1><<<dim3(512), 256, 0, stream>>>(
        attb, wprojT, bproj, C_, C_, nullptr, nullptr, nullptr, nullptr, nullptr, out);
}